// Round 8
// baseline (296.282 us; speedup 1.0000x reference)
//
#include <hip/hip_runtime.h>
#include <hip/hip_bf16.h>

#define NN 10000
#define TT 8
#define LL 3
#define NGRP 625     // 10000 / 16 exactly

// out layout: ys [N][T][64] = 5,120,000 f32 | h [N][64] = 640,000 | c [N][64]
#define OUT_ELEMS 6400000
#define H_OFF 5120000
#define C_OFF 5760000

typedef __bf16 bf16;
typedef __attribute__((ext_vector_type(8))) __bf16 bf16x8;
typedef __attribute__((ext_vector_type(4))) float f32x4;
typedef __attribute__((ext_vector_type(16))) float f32x16;

// v_rcp_f32 (1 instr) instead of IEEE divide — bf16-grade accuracy (verified r4).
__device__ __forceinline__ float sigf(float x) {
    return __builtin_amdgcn_rcpf(1.0f + __expf(-x));
}
__device__ __forceinline__ float tanhf_(float x) {
    return fmaf(2.0f, __builtin_amdgcn_rcpf(1.0f + __expf(-2.0f * x)), -1.0f);
}

// Exact float atomic max via CAS. out is pre-initialized to -inf, exactly 3
// writers per address -> ~1-2 CAS iterations. Bit-equality loop is exact.
__device__ __forceinline__ void atomicFmax(float* addr, float val) {
    unsigned* ua = (unsigned*)addr;
    unsigned old = 0xFF800000u;   // assume -inf (the init value)
    const unsigned vbits = __float_as_uint(val);
    while (true) {
        const unsigned assumed = old;
        old = atomicCAS(ua, assumed, vbits);
        if (old == assumed) break;                 // our value stored
        if (__uint_as_float(old) >= val) break;    // existing is >= ours
    }
}

// ---------------------------------------------------------------------------
// prep_init: (a) repack LSTM weights into bf16 B-fragment order + combine
// biases; (b) initialize ALL of d_out to -inf for the atomic-fmax merge.
// Grid 6250 x 256: thread gid writes f32x4 at gid (6250*256*4 == OUT_ELEMS).
// wts layout (bf16): [l][mat][kh][nt][n16][k32]
// ---------------------------------------------------------------------------
__global__ __launch_bounds__(256) void prep_init_kernel(
    const float* __restrict__ W_ih, const float* __restrict__ W_hh,
    const float* __restrict__ b_ih, const float* __restrict__ b_hh,
    bf16* __restrict__ wts, float* __restrict__ bias,
    float* __restrict__ out) {
    const int id = blockIdx.x * 256 + threadIdx.x;

    // out init: every thread stores one f32x4 of -inf
    const float ninf = __uint_as_float(0xFF800000u);
    ((f32x4*)out)[id] = (f32x4){ninf, ninf, ninf, ninf};

    if (id < LL * 2 * 256 * 64) {
        int col = id & 63;
        int row = (id >> 6) & 255;
        int mat = (id >> 14) & 1;
        int l = id >> 15;
        const float* src = mat ? W_hh : W_ih;
        float w = src[(l * 256 + row) * 64 + col];
        int kh = col >> 5, nt = row >> 4, nn = row & 15, kk = col & 31;
        wts[((((l * 2 + mat) * 2 + kh) * 16 + nt) * 16 + nn) * 32 + kk] = (bf16)w;
    } else if (id < LL * 2 * 256 * 64 + LL * 256) {
        int id2 = id - LL * 2 * 256 * 64;
        bias[id2] = b_ih[id2] + b_hh[id2];
    }
}

// ---------------------------------------------------------------------------
// fused_split: grid = 3*625; block = (level, 16 nodes); 256 thr (4 waves).
// conv: 32x32x16 MFMA (M = 2 nodes x 16 nbrs, K = C = 16 exact) -> LDS feat.
// Chunk loop MUST stay unroll 1 (full unroll pipelines ~272 VGPRs of loads ->
// scratch spill -> 480 MB HBM; measured r5).
// lstm: wave wv owns gate tiles {wv,4+wv,8+wv,12+wv}; 16 weight frags in
// registers (64 VGPRs); 16 MFMAs + 1 barrier per step; rcp cell.
// Epilogue: atomic-fmax directly into out (max over the 3 levels).
// ---------------------------------------------------------------------------
__global__ __launch_bounds__(256, 3) void fused_split_kernel(
    const float* __restrict__ X, const int* __restrict__ As,
    const float* __restrict__ conv_w, const float* __restrict__ conv_b,
    const bf16* __restrict__ wts, const float* __restrict__ bias,
    float* __restrict__ out) {
    __shared__ __align__(16) bf16 featL[TT][16][72];   // 18.4 KB
    __shared__ __align__(16) bf16 hlds[2][16][72];     // 4.6 KB

    const int tid = threadIdx.x;
    const int l = blockIdx.x % 3;
    const int grp = blockIdx.x / 3;
    const int node0 = grp * 16;

    const int lane = tid & 63;
    const int wv = tid >> 6;        // 0..3
    const int c16 = lane & 15;
    const int q = lane >> 4;
    const int m = lane & 31;        // conv: A row = (node-in-pair)<<4 | nbr
    const int hh = lane >> 5;       // conv: k-half
    const int ch0 = hh * 8;
    const int nsub = m >> 4;
    const int kn = m & 15;

    // ================= conv stage =================
    bf16x8 B0, B1;
    {
        const float* w0 = conv_w + ((l * 64 + m) * 16 + ch0);
        f32x4 a = *(const f32x4*)w0, b = *(const f32x4*)(w0 + 4);
        const float* w1 = conv_w + ((l * 64 + 32 + m) * 16 + ch0);
        f32x4 c = *(const f32x4*)w1, d = *(const f32x4*)(w1 + 4);
#pragma unroll
        for (int j = 0; j < 4; ++j) {
            B0[j] = (bf16)a[j]; B0[4 + j] = (bf16)b[j];
            B1[j] = (bf16)c[j]; B1[4 + j] = (bf16)d[j];
        }
    }
    const float cb0 = conv_b[l * 64 + m];
    const float cb1 = conv_b[l * 64 + 32 + m];

#pragma unroll 1
    for (int c = 0; c < 4; ++c) {
        const int pc = 2 * wv + (c & 1);
        const int t0 = (c >> 1) * 4;
        const int gn = node0 + 2 * pc + nsub;

        int aidx[4];
#pragma unroll
        for (int j = 0; j < 4; ++j)
            aidx[j] = As[((long)(l * 8 + t0 + j) * NN + gn) * 16 + kn];
        f32x4 sv[4][2], gv[4][2];
#pragma unroll
        for (int j = 0; j < 4; ++j) {
            const float* sp = X + ((gn * 8 + t0 + j) * 16 + ch0);
            sv[j][0] = *(const f32x4*)sp;
            sv[j][1] = *(const f32x4*)(sp + 4);
        }
#pragma unroll
        for (int j = 0; j < 4; ++j) {
            const float* gp = X + (((long)aidx[j] * 8 + t0 + j) * 16 + ch0);
            gv[j][0] = *(const f32x4*)gp;
            gv[j][1] = *(const f32x4*)(gp + 4);
        }

#pragma unroll
        for (int j = 0; j < 4; ++j) {
            bf16x8 af;
#pragma unroll
            for (int k = 0; k < 4; ++k) {
                af[k]     = (bf16)(gv[j][0][k] - sv[j][0][k]);
                af[4 + k] = (bf16)(gv[j][1][k] - sv[j][1][k]);
            }
            f32x16 D0, D1;
#pragma unroll
            for (int k = 0; k < 16; ++k) { D0[k] = 0.0f; D1[k] = 0.0f; }
            D0 = __builtin_amdgcn_mfma_f32_32x32x16_bf16(af, B0, D0, 0, 0, 0);
            D1 = __builtin_amdgcn_mfma_f32_32x32x16_bf16(af, B1, D1, 0, 0, 0);

            float v00 = D0[0], v01 = D1[0], v10 = D0[8], v11 = D1[8];
#pragma unroll
            for (int k = 1; k < 8; ++k) {
                v00 = fmaxf(v00, D0[k]);     v01 = fmaxf(v01, D1[k]);
                v10 = fmaxf(v10, D0[8 + k]); v11 = fmaxf(v11, D1[8 + k]);
            }
            v00 = fmaxf(v00, __shfl_xor(v00, 32));
            v01 = fmaxf(v01, __shfl_xor(v01, 32));
            v10 = fmaxf(v10, __shfl_xor(v10, 32));
            v11 = fmaxf(v11, __shfl_xor(v11, 32));

            const float sA = hh ? v10 : v00;   // cols [0,32)
            const float sB = hh ? v11 : v01;   // cols [32,64)
            featL[t0 + j][2 * pc + hh][m]      = (bf16)(sA + cb0);
            featL[t0 + j][2 * pc + hh][32 + m] = (bf16)(sB + cb1);
        }
    }

    // ================= LSTM weights (registers, 64 VGPRs) =================
    const bf16* wb = wts + l * 32768;
    const int fo = c16 * 32 + q * 8;
    bf16x8 Bx0[4], Bx1[4], Bh0[4], Bh1[4];
    float brg[4];
#pragma unroll
    for (int g = 0; g < 4; ++g) {
        const int nt = 4 * g + wv;
        Bx0[g] = *(const bf16x8*)(wb + (0 * 16 + nt) * 512 + fo);
        Bx1[g] = *(const bf16x8*)(wb + (1 * 16 + nt) * 512 + fo);
        Bh0[g] = *(const bf16x8*)(wb + (2 * 16 + nt) * 512 + fo);
        Bh1[g] = *(const bf16x8*)(wb + (3 * 16 + nt) * 512 + fo);
        brg[g] = bias[l * 256 + nt * 16 + c16];
    }
    float c_r[4];
#pragma unroll
    for (int r = 0; r < 4; ++r) c_r[r] = 0.0f;

    float ymax[TT][4], hfin[4], cfin[4];

    // ================= 8 recurrent steps =================
#pragma unroll
    for (int t = 0; t < TT; ++t) {
        __syncthreads();  // t=0: featL ready; t>0: h(t-1) visible

        bf16x8 ax0 = *(const bf16x8*)&featL[t][c16][q * 8];
        bf16x8 ax1 = *(const bf16x8*)&featL[t][c16][32 + q * 8];
        bf16x8 ah0, ah1;
        if (t > 0) {
            ah0 = *(const bf16x8*)&hlds[(t + 1) & 1][c16][q * 8];
            ah1 = *(const bf16x8*)&hlds[(t + 1) & 1][c16][32 + q * 8];
        }

        f32x4 acc[4];
#pragma unroll
        for (int g = 0; g < 4; ++g) {
            float b = brg[g];
            acc[g] = (f32x4){b, b, b, b};
            acc[g] = __builtin_amdgcn_mfma_f32_16x16x32_bf16(ax0, Bx0[g], acc[g], 0, 0, 0);
            acc[g] = __builtin_amdgcn_mfma_f32_16x16x32_bf16(ax1, Bx1[g], acc[g], 0, 0, 0);
            if (t > 0) {
                acc[g] = __builtin_amdgcn_mfma_f32_16x16x32_bf16(ah0, Bh0[g], acc[g], 0, 0, 0);
                acc[g] = __builtin_amdgcn_mfma_f32_16x16x32_bf16(ah1, Bh1[g], acc[g], 0, 0, 0);
            }
        }

        // cell: lane holds nodes q*4+r, hidden col wv*16+c16
#pragma unroll
        for (int r = 0; r < 4; ++r) {
            float iv = acc[0][r], fv = acc[1][r], gg = acc[2][r], ov = acc[3][r];
            float c = sigf(fv) * c_r[r] + sigf(iv) * tanhf_(gg);
            c_r[r] = c;
            float h = sigf(ov) * tanhf_(c);
            hlds[t & 1][q * 4 + r][wv * 16 + c16] = (bf16)h;
            ymax[t][r] = h;
            if (t == TT - 1) { hfin[r] = h; cfin[r] = c; }
        }
    }

    // ================= epilogue: atomic max-over-L into out =================
    const int col = wv * 16 + c16;
#pragma unroll
    for (int t = 0; t < TT; ++t)
#pragma unroll
        for (int r = 0; r < 4; ++r)
            atomicFmax(&out[((long)(node0 + q * 4 + r) * 8 + t) * 64 + col],
                       ymax[t][r]);
    float* sh = out + (long)H_OFF;
    float* sc = out + (long)C_OFF;
#pragma unroll
    for (int r = 0; r < 4; ++r) {
        atomicFmax(&sh[(long)(node0 + q * 4 + r) * 64 + col], hfin[r]);
        atomicFmax(&sc[(long)(node0 + q * 4 + r) * 64 + col], cfin[r]);
    }
}

extern "C" void kernel_launch(void* const* d_in, const int* in_sizes, int n_in,
                              void* d_out, int out_size, void* d_ws, size_t ws_size,
                              hipStream_t stream) {
    const float* X = (const float*)d_in[0];
    const int* As = (const int*)d_in[1];
    const float* conv_w = (const float*)d_in[4];
    const float* conv_b = (const float*)d_in[5];
    const float* W_ih = (const float*)d_in[6];
    const float* W_hh = (const float*)d_in[7];
    const float* b_ih = (const float*)d_in[8];
    const float* b_hh = (const float*)d_in[9];
    float* out = (float*)d_out;

    char* ws = (char*)d_ws;
    bf16* wts = (bf16*)ws;                      // 98,304 bf16 = 196,608 B
    float* bias = (float*)(ws + 196608);        // 768 f32

    // 6250*256 threads x f32x4 == 6,400,000 floats == out_size exactly
    hipLaunchKernelGGL(prep_init_kernel, dim3(6250), dim3(256), 0, stream,
                       W_ih, W_hh, b_ih, b_hh, wts, bias, out);
    hipLaunchKernelGGL(fused_split_kernel, dim3(3 * NGRP), dim3(256), 0, stream,
                       X, As, conv_w, conv_b, wts, bias, out);
}